// Round 15
// baseline (118.344 us; speedup 1.0000x reference)
//
#include <hip/hip_runtime.h>
#include <hip/hip_bf16.h>
#include <stdint.h>

typedef __bf16 bf16_t;
typedef __bf16 bf16x8 __attribute__((ext_vector_type(8)));
typedef float f32x4 __attribute__((ext_vector_type(4)));

#define MFMA_16x16x32(A, B, C) __builtin_amdgcn_mfma_f32_16x16x32_bf16((A), (B), (C), 0, 0, 0)

__device__ inline void gload_lds16(const bf16_t* g, bf16_t* lds) {
  auto* gp = (const __attribute__((address_space(1))) uint32_t*)(uintptr_t)g;
  auto* lp = (__attribute__((address_space(3))) uint32_t*)(uintptr_t)lds;
  __builtin_amdgcn_global_load_lds(gp, lp, 16, 0, 0);
}

// ---------- H partials, 256x256 tile, 16 waves (1024 thr), f32-direct, split-K=8 ----------
// Same tile/LDS/swizzle/barrier structure as the verified 8-wave body; waves doubled
// for TLP (4 waves/SIMD) at IDENTICAL memory demand.  Wave grid 4x4 of 64x64.
__global__ __launch_bounds__(1024, 4)
void k_gram256(const float* __restrict__ A, const float* __restrict__ B,
               bf16_t* __restrict__ Cp) {
  const int raw = blockIdx.x;              // 256 blocks
  const int xcd = raw & 7, idx = raw >> 3; // XCD-affine: xcd = batch
  const int mt = idx & 1, nt = (idx >> 1) & 1, ks = idx >> 2;  // ks 0..7
  const int b = xcd;
  const float* Ab = A + (size_t)b * 512 * 4096;
  const float* Bb = B + (size_t)b * 512 * 4096;
  const int bm = mt * 256, bn = nt * 256;
  const int kbeg = ks * 512;               // 16 steps of BK=32

  const int tid = threadIdx.x;
  const int wave = tid >> 6, lane = tid & 63;
  const int l15 = lane & 15, l4 = lane >> 4;
  const int wm = (wave >> 2) * 64, wn = (wave & 3) * 64;
  const int rsw = (l15 >> 1) & 3;          // read swizzle

  __shared__ bf16_t As[2][256 * 32];
  __shared__ bf16_t Bs[2][256 * 32];

  f32x4 acc[4][4] = {};

  // staging: thread -> row srow (0..255), 16B chunk q4 (0..3)
  const int srow = tid >> 2, q4 = tid & 3;
  const int sw = (srow >> 1) & 3;
  const int wo = srow * 32 + ((q4 ^ sw) * 8);   // one uint4 per tile per thread
  const float* ga = Ab + (size_t)(bm + srow) * 4096 + kbeg + q4 * 8;
  const float* gb = Bb + (size_t)(bn + srow) * 4096 + kbeg + q4 * 8;

  float4 ra0, ra1, rb0, rb1;
  ra0 = *(const float4*)(ga);     ra1 = *(const float4*)(ga + 4);
  rb0 = *(const float4*)(gb);     rb1 = *(const float4*)(gb + 4);

  int cur = 0;
#pragma unroll 1
  for (int i = 0; i < 16; ++i) {
    bf16_t ta[8], tb[8];
    ta[0] = (bf16_t)ra0.x; ta[1] = (bf16_t)ra0.y; ta[2] = (bf16_t)ra0.z; ta[3] = (bf16_t)ra0.w;
    ta[4] = (bf16_t)ra1.x; ta[5] = (bf16_t)ra1.y; ta[6] = (bf16_t)ra1.z; ta[7] = (bf16_t)ra1.w;
    tb[0] = (bf16_t)rb0.x; tb[1] = (bf16_t)rb0.y; tb[2] = (bf16_t)rb0.z; tb[3] = (bf16_t)rb0.w;
    tb[4] = (bf16_t)rb1.x; tb[5] = (bf16_t)rb1.y; tb[6] = (bf16_t)rb1.z; tb[7] = (bf16_t)rb1.w;
    *(uint4*)(&As[cur][wo]) = *(uint4*)(ta);
    *(uint4*)(&Bs[cur][wo]) = *(uint4*)(tb);
    if (i + 1 < 16) {                       // prefetch step i+1
      const float* na = ga + (i + 1) * 32;
      const float* nb = gb + (i + 1) * 32;
      ra0 = *(const float4*)(na);  ra1 = *(const float4*)(na + 4);
      rb0 = *(const float4*)(nb);  rb1 = *(const float4*)(nb + 4);
    }
    __syncthreads();                        // writes(cur) visible; buf protection per dbuf
    bf16x8 bfr[4];
#pragma unroll
    for (int n = 0; n < 4; ++n)
      bfr[n] = *(const bf16x8*)(&Bs[cur][(wn + n * 16 + l15) * 32 + ((l4 ^ rsw) * 8)]);
#pragma unroll
    for (int m = 0; m < 4; ++m) {
      bf16x8 af = *(const bf16x8*)(&As[cur][(wm + m * 16 + l15) * 32 + ((l4 ^ rsw) * 8)]);
#pragma unroll
      for (int n = 0; n < 4; ++n)
        acc[m][n] = MFMA_16x16x32(af, bfr[n], acc[m][n]);
    }
    cur ^= 1;
  }

  bf16_t* Cb = Cp + (size_t)(b * 8 + ks) * 262144;
#pragma unroll
  for (int m = 0; m < 4; ++m) {
    const int row0 = bm + wm + m * 16 + l4 * 4;
#pragma unroll
    for (int n = 0; n < 4; ++n) {
      const int col = bn + wn + n * 16 + l15;
#pragma unroll
      for (int j = 0; j < 4; ++j)
        Cb[(size_t)(row0 + j) * 512 + col] = (bf16_t)acc[m][n][j];
    }
  }
}

// ---------- reduce8 + weight-prep roles (256-thread blocks) ----------
// [0,1024): reduce 8 bf16 partials -> Hb.  [1024,1792): cvt3.  [1792,2048): wvT.
__global__ __launch_bounds__(256)
void k_reduce_prep(const bf16_t* __restrict__ p, bf16_t* __restrict__ out,
                   const float* __restrict__ Wq, const float* __restrict__ Wkv,
                   const float* __restrict__ Wout,
                   bf16_t* __restrict__ wq_b, bf16_t* __restrict__ wk_b,
                   bf16_t* __restrict__ wout_b, bf16_t* __restrict__ wvT) {
  __shared__ float tile[32][33];
  const int bid = blockIdx.x;
  const int tid = threadIdx.x;

  if (bid < 1024) {
    int i = bid * 256 + tid;
    int b = i >> 15;
    int e8 = (i & 32767) * 8;
    const bf16_t* pb = p + (size_t)b * 8 * 262144 + e8;
    float s[8] = {};
#pragma unroll
    for (int ks = 0; ks < 8; ++ks) {
      bf16x8 v = *(const bf16x8*)(pb + (size_t)ks * 262144);
#pragma unroll
      for (int j = 0; j < 8; ++j) s[j] += (float)v[j];
    }
    bf16x8 o;
#pragma unroll
    for (int j = 0; j < 8; ++j) o[j] = (bf16_t)s[j];
    *(bf16x8*)(out + (size_t)b * 262144 + e8) = o;
  } else if (bid < 1792) {
    int i = (bid - 1024) * 256 + tid;
    int region = i >> 16;
    int e = (i & 65535) * 4;
    const float* src = region == 0 ? Wq : (region == 1 ? Wkv : Wout);
    bf16_t* dst = region == 0 ? wq_b : (region == 1 ? wk_b : wout_b);
    float4 v = *(const float4*)(src + e);
    bf16_t o[4] = {(bf16_t)v.x, (bf16_t)v.y, (bf16_t)v.z, (bf16_t)v.w};
    *(uint2*)(dst + e) = *(uint2*)o;
  } else {
    const int rel = bid - 1792;
    const int x = rel & 15, yy = (rel >> 4) & 1, z = rel >> 5;
    const int C = 64, N = 512;
    const float* src = Wkv + (size_t)512 * 512 + (size_t)z * C * N;
    bf16_t* dst = wvT + (size_t)z * C * N;
    const int n0 = x * 32, c0 = yy * 32;
    const int tx = tid & 31, ty = tid >> 5;
#pragma unroll
    for (int i = 0; i < 32; i += 8)
      tile[ty + i][tx] = src[(size_t)(c0 + ty + i) * N + (n0 + tx)];
    __syncthreads();
#pragma unroll
    for (int i = 0; i < 32; i += 8)
      dst[(size_t)(n0 + ty + i) * C + (c0 + tx)] = (bf16_t)tile[tx][ty + i];
  }
}

// ---------- small GEMM C[M][N] = A[M][K] B[N][K]^T, 128x128, dbuf (bf16 out) ----------
__global__ __launch_bounds__(256)
void k_gemm_bt(const bf16_t* __restrict__ A, const bf16_t* __restrict__ B,
               bf16_t* __restrict__ Cv, int M, int N, int K,
               long long sA, long long sB, long long sC) {
  const int zb = blockIdx.z;
  A += (size_t)zb * sA;
  B += (size_t)zb * sB;

  const int tid = threadIdx.x;
  const int wave = tid >> 6, lane = tid & 63;
  const int l15 = lane & 15, l4 = lane >> 4;
  const int bm = blockIdx.y * 128, bn = blockIdx.x * 128;
  const int wm = (wave >> 1) * 64, wn = (wave & 1) * 64;

  __shared__ bf16_t As[2][128 * 32];
  __shared__ bf16_t Bs[2][128 * 32];

  f32x4 acc[4][4] = {};

  const int lrow = lane >> 2;
  const int lchunk = (lane & 3) * 8;
  const int ra = wave * 16 + lrow;

  auto stage = [&](int buf, int k0) {
    gload_lds16(&A[(size_t)(bm + ra) * K + k0 + lchunk],      &As[buf][(wave * 16) * 32]);
    gload_lds16(&A[(size_t)(bm + 64 + ra) * K + k0 + lchunk], &As[buf][(64 + wave * 16) * 32]);
    gload_lds16(&B[(size_t)(bn + ra) * K + k0 + lchunk],      &Bs[buf][(wave * 16) * 32]);
    gload_lds16(&B[(size_t)(bn + 64 + ra) * K + k0 + lchunk], &Bs[buf][(64 + wave * 16) * 32]);
  };

  const int nsteps = K / 32;
  stage(0, 0);
  __syncthreads();

  for (int i = 0; i < nsteps; ++i) {
    const int cur = i & 1;
    if (i + 1 < nsteps) stage(cur ^ 1, (i + 1) * 32);
    bf16x8 af[4], bfr[4];
#pragma unroll
    for (int m = 0; m < 4; ++m)
      af[m] = *(const bf16x8*)(&As[cur][(wm + m * 16 + l15) * 32 + l4 * 8]);
#pragma unroll
    for (int n = 0; n < 4; ++n)
      bfr[n] = *(const bf16x8*)(&Bs[cur][(wn + n * 16 + l15) * 32 + l4 * 8]);
#pragma unroll
    for (int m = 0; m < 4; ++m)
#pragma unroll
      for (int n = 0; n < 4; ++n)
        acc[m][n] = MFMA_16x16x32(af[m], bfr[n], acc[m][n]);
    __syncthreads();
  }

#pragma unroll
  for (int m = 0; m < 4; ++m) {
    const int row0 = bm + wm + m * 16 + l4 * 4;
#pragma unroll
    for (int n = 0; n < 4; ++n) {
      const int col = bn + wn + n * 16 + l15;
#pragma unroll
      for (int j = 0; j < 4; ++j)
        (Cv + (size_t)zb * sC)[(size_t)(row0 + j) * N + col] = (bf16_t)acc[m][n][j];
    }
  }
}

// ---------- fused dots + softmax + wveff: one block per (b,h) ----------
__global__ __launch_bounds__(256)
void k_dots_wveff(const bf16_t* __restrict__ T1, const bf16_t* __restrict__ wk,
                  const bf16_t* __restrict__ wvT, bf16_t* __restrict__ wveffT) {
  const int bh = blockIdx.x;
  const int b = bh >> 3, hh = bh & 7;
  const bf16_t* qh = T1 + (size_t)b * 262144 + (size_t)hh * 64 * 512;
  const bf16_t* kh = wk + (size_t)hh * 64 * 512;
  const int tid = threadIdx.x;
  const int wave = tid >> 6, lane = tid & 63;
  const int l15 = lane & 15, l4 = lane >> 4;

  __shared__ float S[64][65];
  __shared__ bf16_t P[64][72];

  {
    const int wm = (wave >> 1) * 32, wn = (wave & 1) * 32;
    f32x4 acc[2][2] = {};
#pragma unroll 2
    for (int k0 = 0; k0 < 512; k0 += 32) {
      bf16x8 af[2], bfr[2];
#pragma unroll
      for (int m = 0; m < 2; ++m)
        af[m] = *(const bf16x8*)(&qh[(size_t)(wm + m * 16 + l15) * 512 + k0 + l4 * 8]);
#pragma unroll
      for (int n = 0; n < 2; ++n)
        bfr[n] = *(const bf16x8*)(&kh[(size_t)(wn + n * 16 + l15) * 512 + k0 + l4 * 8]);
#pragma unroll
      for (int m = 0; m < 2; ++m)
#pragma unroll
        for (int n = 0; n < 2; ++n)
          acc[m][n] = MFMA_16x16x32(af[m], bfr[n], acc[m][n]);
    }
    const float scale = 0.125f;
#pragma unroll
    for (int m = 0; m < 2; ++m)
#pragma unroll
      for (int n = 0; n < 2; ++n)
#pragma unroll
        for (int j = 0; j < 4; ++j)
          S[wm + m * 16 + l4 * 4 + j][wn + n * 16 + l15] = acc[m][n][j] * scale;
  }
  __syncthreads();

  {
    const int r = tid >> 2, seg = (tid & 3) * 16;
    float vals[16];
    float mx = -1e30f;
#pragma unroll
    for (int c = 0; c < 16; ++c) { vals[c] = S[r][seg + c]; mx = fmaxf(mx, vals[c]); }
    mx = fmaxf(mx, __shfl_xor(mx, 1));
    mx = fmaxf(mx, __shfl_xor(mx, 2));
    float sum = 0.f;
#pragma unroll
    for (int c = 0; c < 16; ++c) { vals[c] = __expf(vals[c] - mx); sum += vals[c]; }
    sum += __shfl_xor(sum, 1);
    sum += __shfl_xor(sum, 2);
    const float inv = 1.0f / sum;
    bf16_t pr[16];
#pragma unroll
    for (int c = 0; c < 16; ++c) pr[c] = (bf16_t)(vals[c] * inv);
    *(uint4*)(&P[r][seg]) = *(uint4*)(pr);
    *(uint4*)(&P[r][seg + 8]) = *(uint4*)(pr + 8);
  }
  __syncthreads();

  {
    const bf16_t* av = wvT + (size_t)hh * 512 * 64;
    bf16_t* ob = wveffT + (size_t)b * 262144 + (size_t)hh * 64;
    const int wm = (wave >> 1) * 64, wn = (wave & 1) * 32;
    for (int cm0 = 0; cm0 < 512; cm0 += 128) {
      f32x4 acc[4][2] = {};
#pragma unroll
      for (int ks = 0; ks < 2; ++ks) {
        const int k0 = ks * 32;
        bf16x8 af[4], bfr[2];
#pragma unroll
        for (int m = 0; m < 4; ++m)
          af[m] = *(const bf16x8*)(&av[(size_t)(cm0 + wm + m * 16 + l15) * 64 + k0 + l4 * 8]);
#pragma unroll
        for (int n = 0; n < 2; ++n)
          bfr[n] = *(const bf16x8*)(&P[wn + n * 16 + l15][k0 + l4 * 8]);
#pragma unroll
        for (int m = 0; m < 4; ++m)
#pragma unroll
          for (int n = 0; n < 2; ++n)
            acc[m][n] = MFMA_16x16x32(af[m], bfr[n], acc[m][n]);
      }
#pragma unroll
      for (int m = 0; m < 4; ++m)
#pragma unroll
        for (int n = 0; n < 2; ++n)
#pragma unroll
          for (int j = 0; j < 4; ++j)
            ob[(size_t)(cm0 + wm + m * 16 + l4 * 4 + j) * 512 + wn + n * 16 + l15] =
                (bf16_t)acc[m][n][j];
    }
  }
}

// ---------- y GEMM from f32 B (round-12 verified): 256x128, in-LDS transpose staging ----------
__global__ __launch_bounds__(512, 2)
void k_yf32(const bf16_t* __restrict__ A, const float* __restrict__ Bf,
            float* __restrict__ C, const float* __restrict__ bias) {
  const int raw = blockIdx.x;              // 512 blocks
  const int b = raw & 7, c = raw >> 3;     // XCD-affine: xcd = batch
  const int bm = (c & 1) * 256, bn = (c >> 1) * 128;   // M=512, N=4096
  A  += (size_t)b * 262144;
  Bf += (size_t)b * 512 * 4096;
  C  += (size_t)b * 512 * 4096;

  const int tid = threadIdx.x;
  const int wave = tid >> 6, lane = tid & 63;
  const int l15 = lane & 15, l4 = lane >> 4;
  const int wm = (wave >> 1) * 64, wn = (wave & 1) * 64;
  const int rsw = (l15 >> 1) & 3;

  __shared__ bf16_t As[2][256 * 32];   // 32 KB
  __shared__ bf16_t Bs[2][128 * 32];   // 16 KB
  __shared__ float  Ft[32 * 128];      // 16 KB

  f32x4 acc[4][4] = {};

  const int lrow = lane >> 2;
  const int lch = (lane & 3) ^ ((lane >> 3) & 3);
  const bf16_t* srcA = A + (size_t)(bm + wave * 32 + lrow) * 512 + lch * 8;
  bf16_t* dstA = &As[0][wave * 32 * 32];
  const int bufA = 256 * 32;

  const int fr = tid >> 4, fc = (tid & 15) * 8;
  const float* srcB = Bf + (size_t)fr * 4096 + bn + fc;

  const int tn = tid >> 2, tc = (tid & 3) * 8;
  const int wchunk = ((tid & 3) ^ ((tn >> 1) & 3)) * 8;

  float4 rb0 = *(const float4*)(srcB);
  float4 rb1 = *(const float4*)(srcB + 4);
  gload_lds16(srcA, dstA);
  gload_lds16(srcA + 16 * 512, dstA + 512);
  __syncthreads();

  int cur = 0;
  for (int i = 0; i < 16; ++i) {
    *(float4*)(&Ft[fr * 128 + fc]) = rb0;
    *(float4*)(&Ft[fr * 128 + fc + 4]) = rb1;
    __syncthreads();
    {
      bf16_t tb[8];
#pragma unroll
      for (int q = 0; q < 8; ++q) tb[q] = (bf16_t)Ft[(tc + q) * 128 + tn];
      *(uint4*)(&Bs[cur][tn * 32 + wchunk]) = *(uint4*)tb;
    }
    __syncthreads();
    if (i + 1 < 16) {
      const float* nb = srcB + (size_t)(i + 1) * 32 * 4096;
      rb0 = *(const float4*)(nb);
      rb1 = *(const float4*)(nb + 4);
      gload_lds16(srcA + (i + 1) * 32,            dstA + (cur ^ 1) * bufA);
      gload_lds16(srcA + 16 * 512 + (i + 1) * 32, dstA + (cur ^ 1) * bufA + 512);
    }
    bf16x8 af[4], bfr[4];
#pragma unroll
    for (int n = 0; n < 4; ++n)
      bfr[n] = *(const bf16x8*)(&Bs[cur][(wn + n * 16 + l15) * 32 + ((l4 ^ rsw) * 8)]);
#pragma unroll
    for (int m = 0; m < 4; ++m)
      af[m] = *(const bf16x8*)(&As[cur][(wm + m * 16 + l15) * 32 + ((l4 ^ rsw) * 8)]);
#pragma unroll
    for (int m = 0; m < 4; ++m)
#pragma unroll
      for (int n = 0; n < 4; ++n)
        acc[m][n] = MFMA_16x16x32(af[m], bfr[n], acc[m][n]);
    cur ^= 1;
  }

#pragma unroll
  for (int m = 0; m < 4; ++m) {
    const int row0 = bm + wm + m * 16 + l4 * 4;
#pragma unroll
    for (int n = 0; n < 4; ++n) {
      const int col = bn + wn + n * 16 + l15;
#pragma unroll
      for (int j = 0; j < 4; ++j)
        C[(size_t)(row0 + j) * 4096 + col] = acc[m][n][j] + bias[row0 + j];
    }
  }
}

extern "C" void kernel_launch(void* const* d_in, const int* in_sizes, int n_in,
                              void* d_out, int out_size, void* d_ws, size_t ws_size,
                              hipStream_t stream) {
  const float* f_m  = (const float*)d_in[0];
  const float* f_n  = (const float*)d_in[1];
  const float* Wq   = (const float*)d_in[2];
  const float* Wkv  = (const float*)d_in[3];
  const float* Wout = (const float*)d_in[4];
  const float* bout = (const float*)d_in[5];
  float* y = (float*)d_out;

  const size_t SQ  = (size_t)512 * 512;
  char* p = (char*)d_ws;
  bf16_t* wq_b    = (bf16_t*)p; p += SQ * 2;
  bf16_t* wk_b    = (bf16_t*)p; p += SQ * 2;
  bf16_t* wout_b  = (bf16_t*)p; p += SQ * 2;
  bf16_t* wvT     = (bf16_t*)p; p += SQ * 2;               // [h][c][64]
  bf16_t* Hb      = (bf16_t*)p; p += (size_t)8 * SQ * 2;   // [b][c'][c]
  bf16_t* T1      = (bf16_t*)p; p += (size_t)8 * SQ * 2;   // [b][hi][c']
  bf16_t* wveffT  = (bf16_t*)p; p += (size_t)8 * SQ * 2;   // [b][c][hi]
  bf16_t* W2      = (bf16_t*)p; p += (size_t)8 * SQ * 2;   // [b][o][c]
  bf16_t* Hp8     = (bf16_t*)p; p += (size_t)64 * SQ * 2;  // bf16 split-8 partials

  // gram: 16 waves/block for TLP (same tile, same traffic)
  k_gram256<<<dim3(256), 1024, 0, stream>>>(f_n, f_m, Hp8);
  // reduce8 + weight cvt + Wv transpose in one grid
  k_reduce_prep<<<dim3(2048), 256, 0, stream>>>(Hp8, Hb, Wq, Wkv, Wout,
                                                wq_b, wk_b, wout_b, wvT);

  // T1[b][hi][c'] = sum_c Wq[hi][c] H[b][c'][c]
  k_gemm_bt<<<dim3(4, 4, 8), 256, 0, stream>>>(wq_b, Hb, T1, 512, 512, 512,
                                               0, (long long)SQ, (long long)SQ);
  // dots + softmax + wveff fused
  k_dots_wveff<<<dim3(64), 256, 0, stream>>>(T1, wk_b, wvT, wveffT);
  // W2[b][o][c] = sum_hi Wout[o][hi] WvEffT[b][c][hi]
  k_gemm_bt<<<dim3(4, 4, 8), 256, 0, stream>>>(wout_b, wveffT, W2, 512, 512, 512,
                                               0, (long long)SQ, (long long)SQ);
  // y from f32 f_n directly (in-LDS transpose staging), 256x128 tiles
  k_yf32<<<dim3(512), 512, 0, stream>>>(W2, f_n, y, bout);
}

// Round 16
// 111.180 us; speedup vs baseline: 1.0644x; 1.0644x over previous
//
#include <hip/hip_runtime.h>
#include <hip/hip_bf16.h>
#include <stdint.h>

typedef __bf16 bf16_t;
typedef __bf16 bf16x8 __attribute__((ext_vector_type(8)));
typedef float f32x4 __attribute__((ext_vector_type(4)));

#define MFMA_16x16x32(A, B, C) __builtin_amdgcn_mfma_f32_16x16x32_bf16((A), (B), (C), 0, 0, 0)

__device__ inline void gload_lds16(const bf16_t* g, bf16_t* lds) {
  auto* gp = (const __attribute__((address_space(1))) uint32_t*)(uintptr_t)g;
  auto* lp = (__attribute__((address_space(3))) uint32_t*)(uintptr_t)lds;
  __builtin_amdgcn_global_load_lds(gp, lp, 16, 0, 0);
}

// ---------- H partials, 256x256 tile, 8 waves, f32-direct, split-K=8 ----------
// 2-deep register prefetch (loads for step i+2 issued at step i; two named reg
// sets, 2-step unrolled loop -> all indexing static).  Round-14 verified best.
__global__ __launch_bounds__(512, 2)
void k_gram256(const float* __restrict__ A, const float* __restrict__ B,
               bf16_t* __restrict__ Cp) {
  const int raw = blockIdx.x;              // 256 blocks
  const int xcd = raw & 7, idx = raw >> 3; // XCD-affine: xcd = batch
  const int mt = idx & 1, nt = (idx >> 1) & 1, ks = idx >> 2;  // ks 0..7
  const int b = xcd;
  const float* Ab = A + (size_t)b * 512 * 4096;
  const float* Bb = B + (size_t)b * 512 * 4096;
  const int bm = mt * 256, bn = nt * 256;
  const int kbeg = ks * 512;               // 16 steps of BK=32

  const int tid = threadIdx.x;
  const int wave = tid >> 6, lane = tid & 63;
  const int l15 = lane & 15, l4 = lane >> 4;
  const int wm = (wave >> 2) * 128, wn = (wave & 3) * 64;
  const int rsw = (l15 >> 1) & 3;

  __shared__ bf16_t As[2][256 * 32];
  __shared__ bf16_t Bs[2][256 * 32];

  f32x4 acc[8][4] = {};

  const int rho = tid >> 1, h = tid & 1;
  const int sw = (rho >> 1) & 3;
  const int wo0 = rho * 32 + (((2 * h) ^ sw) * 8);
  const int wo1 = rho * 32 + (((2 * h + 1) ^ sw) * 8);
  const float* ga = Ab + (size_t)(bm + rho) * 4096 + kbeg + h * 16;
  const float* gb = Bb + (size_t)(bn + rho) * 4096 + kbeg + h * 16;

  // two register prefetch sets (static names -> no scratch, rule #20)
  float4 raA[4], rbA[4], raB[4], rbB[4];
#pragma unroll
  for (int q = 0; q < 4; ++q) {            // step 0 -> set A
    raA[q] = *(const float4*)(ga + q * 4);
    rbA[q] = *(const float4*)(gb + q * 4);
  }
#pragma unroll
  for (int q = 0; q < 4; ++q) {            // step 1 -> set B
    raB[q] = *(const float4*)(ga + 32 + q * 4);
    rbB[q] = *(const float4*)(gb + 32 + q * 4);
  }

#pragma unroll 1
  for (int i = 0; i < 16; i += 2) {
    // ======== step i (even): buffer 0, register set A ========
    {
      bf16_t ta[16], tb[16];
#pragma unroll
      for (int q = 0; q < 4; ++q) {
        ta[q * 4 + 0] = (bf16_t)raA[q].x; ta[q * 4 + 1] = (bf16_t)raA[q].y;
        ta[q * 4 + 2] = (bf16_t)raA[q].z; ta[q * 4 + 3] = (bf16_t)raA[q].w;
        tb[q * 4 + 0] = (bf16_t)rbA[q].x; tb[q * 4 + 1] = (bf16_t)rbA[q].y;
        tb[q * 4 + 2] = (bf16_t)rbA[q].z; tb[q * 4 + 3] = (bf16_t)rbA[q].w;
      }
      *(uint4*)(&As[0][wo0]) = *(uint4*)(ta);
      *(uint4*)(&As[0][wo1]) = *(uint4*)(ta + 8);
      *(uint4*)(&Bs[0][wo0]) = *(uint4*)(tb);
      *(uint4*)(&Bs[0][wo1]) = *(uint4*)(tb + 8);
      if (i + 2 < 16) {                    // prefetch step i+2 -> set A
        const float* na = ga + (i + 2) * 32;
        const float* nb = gb + (i + 2) * 32;
#pragma unroll
        for (int q = 0; q < 4; ++q) {
          raA[q] = *(const float4*)(na + q * 4);
          rbA[q] = *(const float4*)(nb + q * 4);
        }
      }
      __syncthreads();
      bf16x8 bfr[4];
#pragma unroll
      for (int n = 0; n < 4; ++n)
        bfr[n] = *(const bf16x8*)(&Bs[0][(wn + n * 16 + l15) * 32 + ((l4 ^ rsw) * 8)]);
#pragma unroll
      for (int m = 0; m < 8; ++m) {
        bf16x8 af = *(const bf16x8*)(&As[0][(wm + m * 16 + l15) * 32 + ((l4 ^ rsw) * 8)]);
#pragma unroll
        for (int n = 0; n < 4; ++n)
          acc[m][n] = MFMA_16x16x32(af, bfr[n], acc[m][n]);
      }
    }
    // ======== step i+1 (odd): buffer 1, register set B ========
    {
      bf16_t ta[16], tb[16];
#pragma unroll
      for (int q = 0; q < 4; ++q) {
        ta[q * 4 + 0] = (bf16_t)raB[q].x; ta[q * 4 + 1] = (bf16_t)raB[q].y;
        ta[q * 4 + 2] = (bf16_t)raB[q].z; ta[q * 4 + 3] = (bf16_t)raB[q].w;
        tb[q * 4 + 0] = (bf16_t)rbB[q].x; tb[q * 4 + 1] = (bf16_t)rbB[q].y;
        tb[q * 4 + 2] = (bf16_t)rbB[q].z; tb[q * 4 + 3] = (bf16_t)rbB[q].w;
      }
      *(uint4*)(&As[1][wo0]) = *(uint4*)(ta);
      *(uint4*)(&As[1][wo1]) = *(uint4*)(ta + 8);
      *(uint4*)(&Bs[1][wo0]) = *(uint4*)(tb);
      *(uint4*)(&Bs[1][wo1]) = *(uint4*)(tb + 8);
      if (i + 3 < 16) {                    // prefetch step i+3 -> set B
        const float* na = ga + (i + 3) * 32;
        const float* nb = gb + (i + 3) * 32;
#pragma unroll
        for (int q = 0; q < 4; ++q) {
          raB[q] = *(const float4*)(na + q * 4);
          rbB[q] = *(const float4*)(nb + q * 4);
        }
      }
      __syncthreads();
      bf16x8 bfr[4];
#pragma unroll
      for (int n = 0; n < 4; ++n)
        bfr[n] = *(const bf16x8*)(&Bs[1][(wn + n * 16 + l15) * 32 + ((l4 ^ rsw) * 8)]);
#pragma unroll
      for (int m = 0; m < 8; ++m) {
        bf16x8 af = *(const bf16x8*)(&As[1][(wm + m * 16 + l15) * 32 + ((l4 ^ rsw) * 8)]);
#pragma unroll
        for (int n = 0; n < 4; ++n)
          acc[m][n] = MFMA_16x16x32(af, bfr[n], acc[m][n]);
      }
    }
  }

  bf16_t* Cb = Cp + (size_t)(b * 8 + ks) * 262144;
#pragma unroll
  for (int m = 0; m < 8; ++m) {
    const int row0 = bm + wm + m * 16 + l4 * 4;
#pragma unroll
    for (int n = 0; n < 4; ++n) {
      const int col = bn + wn + n * 16 + l15;
#pragma unroll
      for (int j = 0; j < 4; ++j)
        Cb[(size_t)(row0 + j) * 512 + col] = (bf16_t)acc[m][n][j];
    }
  }
}

// ---------- reduce8 + weight-prep roles (256-thread blocks) ----------
// [0,1024): reduce 8 bf16 partials -> Hb.  [1024,1792): cvt3.  [1792,2048): wvT.
__global__ __launch_bounds__(256)
void k_reduce_prep(const bf16_t* __restrict__ p, bf16_t* __restrict__ out,
                   const float* __restrict__ Wq, const float* __restrict__ Wkv,
                   const float* __restrict__ Wout,
                   bf16_t* __restrict__ wq_b, bf16_t* __restrict__ wk_b,
                   bf16_t* __restrict__ wout_b, bf16_t* __restrict__ wvT) {
  __shared__ float tile[32][33];
  const int bid = blockIdx.x;
  const int tid = threadIdx.x;

  if (bid < 1024) {
    int i = bid * 256 + tid;
    int b = i >> 15;
    int e8 = (i & 32767) * 8;
    const bf16_t* pb = p + (size_t)b * 8 * 262144 + e8;
    float s[8] = {};
#pragma unroll
    for (int ks = 0; ks < 8; ++ks) {
      bf16x8 v = *(const bf16x8*)(pb + (size_t)ks * 262144);
#pragma unroll
      for (int j = 0; j < 8; ++j) s[j] += (float)v[j];
    }
    bf16x8 o;
#pragma unroll
    for (int j = 0; j < 8; ++j) o[j] = (bf16_t)s[j];
    *(bf16x8*)(out + (size_t)b * 262144 + e8) = o;
  } else if (bid < 1792) {
    int i = (bid - 1024) * 256 + tid;
    int region = i >> 16;
    int e = (i & 65535) * 4;
    const float* src = region == 0 ? Wq : (region == 1 ? Wkv : Wout);
    bf16_t* dst = region == 0 ? wq_b : (region == 1 ? wk_b : wout_b);
    float4 v = *(const float4*)(src + e);
    bf16_t o[4] = {(bf16_t)v.x, (bf16_t)v.y, (bf16_t)v.z, (bf16_t)v.w};
    *(uint2*)(dst + e) = *(uint2*)o;
  } else {
    const int rel = bid - 1792;
    const int x = rel & 15, yy = (rel >> 4) & 1, z = rel >> 5;
    const int C = 64, N = 512;
    const float* src = Wkv + (size_t)512 * 512 + (size_t)z * C * N;
    bf16_t* dst = wvT + (size_t)z * C * N;
    const int n0 = x * 32, c0 = yy * 32;
    const int tx = tid & 31, ty = tid >> 5;
#pragma unroll
    for (int i = 0; i < 32; i += 8)
      tile[ty + i][tx] = src[(size_t)(c0 + ty + i) * N + (n0 + tx)];
    __syncthreads();
#pragma unroll
    for (int i = 0; i < 32; i += 8)
      dst[(size_t)(n0 + ty + i) * C + (c0 + tx)] = (bf16_t)tile[tx][ty + i];
  }
}

// ---------- small GEMM C[M][N] = A[M][K] B[N][K]^T, 128x128, dbuf (bf16 out) ----------
__global__ __launch_bounds__(256)
void k_gemm_bt(const bf16_t* __restrict__ A, const bf16_t* __restrict__ B,
               bf16_t* __restrict__ Cv, int M, int N, int K,
               long long sA, long long sB, long long sC) {
  const int zb = blockIdx.z;
  A += (size_t)zb * sA;
  B += (size_t)zb * sB;

  const int tid = threadIdx.x;
  const int wave = tid >> 6, lane = tid & 63;
  const int l15 = lane & 15, l4 = lane >> 4;
  const int bm = blockIdx.y * 128, bn = blockIdx.x * 128;
  const int wm = (wave >> 1) * 64, wn = (wave & 1) * 64;

  __shared__ bf16_t As[2][128 * 32];
  __shared__ bf16_t Bs[2][128 * 32];

  f32x4 acc[4][4] = {};

  const int lrow = lane >> 2;
  const int lchunk = (lane & 3) * 8;
  const int ra = wave * 16 + lrow;

  auto stage = [&](int buf, int k0) {
    gload_lds16(&A[(size_t)(bm + ra) * K + k0 + lchunk],      &As[buf][(wave * 16) * 32]);
    gload_lds16(&A[(size_t)(bm + 64 + ra) * K + k0 + lchunk], &As[buf][(64 + wave * 16) * 32]);
    gload_lds16(&B[(size_t)(bn + ra) * K + k0 + lchunk],      &Bs[buf][(wave * 16) * 32]);
    gload_lds16(&B[(size_t)(bn + 64 + ra) * K + k0 + lchunk], &Bs[buf][(64 + wave * 16) * 32]);
  };

  const int nsteps = K / 32;
  stage(0, 0);
  __syncthreads();

  for (int i = 0; i < nsteps; ++i) {
    const int cur = i & 1;
    if (i + 1 < nsteps) stage(cur ^ 1, (i + 1) * 32);
    bf16x8 af[4], bfr[4];
#pragma unroll
    for (int m = 0; m < 4; ++m)
      af[m] = *(const bf16x8*)(&As[cur][(wm + m * 16 + l15) * 32 + l4 * 8]);
#pragma unroll
    for (int n = 0; n < 4; ++n)
      bfr[n] = *(const bf16x8*)(&Bs[cur][(wn + n * 16 + l15) * 32 + l4 * 8]);
#pragma unroll
    for (int m = 0; m < 4; ++m)
#pragma unroll
      for (int n = 0; n < 4; ++n)
        acc[m][n] = MFMA_16x16x32(af[m], bfr[n], acc[m][n]);
    __syncthreads();
  }

#pragma unroll
  for (int m = 0; m < 4; ++m) {
    const int row0 = bm + wm + m * 16 + l4 * 4;
#pragma unroll
    for (int n = 0; n < 4; ++n) {
      const int col = bn + wn + n * 16 + l15;
#pragma unroll
      for (int j = 0; j < 4; ++j)
        (Cv + (size_t)zb * sC)[(size_t)(row0 + j) * N + col] = (bf16_t)acc[m][n][j];
    }
  }
}

// ---------- fused dots + softmax + wveff: one block per (b,h) ----------
__global__ __launch_bounds__(256)
void k_dots_wveff(const bf16_t* __restrict__ T1, const bf16_t* __restrict__ wk,
                  const bf16_t* __restrict__ wvT, bf16_t* __restrict__ wveffT) {
  const int bh = blockIdx.x;
  const int b = bh >> 3, hh = bh & 7;
  const bf16_t* qh = T1 + (size_t)b * 262144 + (size_t)hh * 64 * 512;
  const bf16_t* kh = wk + (size_t)hh * 64 * 512;
  const int tid = threadIdx.x;
  const int wave = tid >> 6, lane = tid & 63;
  const int l15 = lane & 15, l4 = lane >> 4;

  __shared__ float S[64][65];
  __shared__ bf16_t P[64][72];

  {
    const int wm = (wave >> 1) * 32, wn = (wave & 1) * 32;
    f32x4 acc[2][2] = {};
#pragma unroll 2
    for (int k0 = 0; k0 < 512; k0 += 32) {
      bf16x8 af[2], bfr[2];
#pragma unroll
      for (int m = 0; m < 2; ++m)
        af[m] = *(const bf16x8*)(&qh[(size_t)(wm + m * 16 + l15) * 512 + k0 + l4 * 8]);
#pragma unroll
      for (int n = 0; n < 2; ++n)
        bfr[n] = *(const bf16x8*)(&kh[(size_t)(wn + n * 16 + l15) * 512 + k0 + l4 * 8]);
#pragma unroll
      for (int m = 0; m < 2; ++m)
#pragma unroll
        for (int n = 0; n < 2; ++n)
          acc[m][n] = MFMA_16x16x32(af[m], bfr[n], acc[m][n]);
    }
    const float scale = 0.125f;
#pragma unroll
    for (int m = 0; m < 2; ++m)
#pragma unroll
      for (int n = 0; n < 2; ++n)
#pragma unroll
        for (int j = 0; j < 4; ++j)
          S[wm + m * 16 + l4 * 4 + j][wn + n * 16 + l15] = acc[m][n][j] * scale;
  }
  __syncthreads();

  {
    const int r = tid >> 2, seg = (tid & 3) * 16;
    float vals[16];
    float mx = -1e30f;
#pragma unroll
    for (int c = 0; c < 16; ++c) { vals[c] = S[r][seg + c]; mx = fmaxf(mx, vals[c]); }
    mx = fmaxf(mx, __shfl_xor(mx, 1));
    mx = fmaxf(mx, __shfl_xor(mx, 2));
    float sum = 0.f;
#pragma unroll
    for (int c = 0; c < 16; ++c) { vals[c] = __expf(vals[c] - mx); sum += vals[c]; }
    sum += __shfl_xor(sum, 1);
    sum += __shfl_xor(sum, 2);
    const float inv = 1.0f / sum;
    bf16_t pr[16];
#pragma unroll
    for (int c = 0; c < 16; ++c) pr[c] = (bf16_t)(vals[c] * inv);
    *(uint4*)(&P[r][seg]) = *(uint4*)(pr);
    *(uint4*)(&P[r][seg + 8]) = *(uint4*)(pr + 8);
  }
  __syncthreads();

  {
    const bf16_t* av = wvT + (size_t)hh * 512 * 64;
    bf16_t* ob = wveffT + (size_t)b * 262144 + (size_t)hh * 64;
    const int wm = (wave >> 1) * 64, wn = (wave & 1) * 32;
    for (int cm0 = 0; cm0 < 512; cm0 += 128) {
      f32x4 acc[4][2] = {};
#pragma unroll
      for (int ks = 0; ks < 2; ++ks) {
        const int k0 = ks * 32;
        bf16x8 af[4], bfr[2];
#pragma unroll
        for (int m = 0; m < 4; ++m)
          af[m] = *(const bf16x8*)(&av[(size_t)(cm0 + wm + m * 16 + l15) * 64 + k0 + l4 * 8]);
#pragma unroll
        for (int n = 0; n < 2; ++n)
          bfr[n] = *(const bf16x8*)(&P[wn + n * 16 + l15][k0 + l4 * 8]);
#pragma unroll
        for (int m = 0; m < 4; ++m)
#pragma unroll
          for (int n = 0; n < 2; ++n)
            acc[m][n] = MFMA_16x16x32(af[m], bfr[n], acc[m][n]);
      }
#pragma unroll
      for (int m = 0; m < 4; ++m)
#pragma unroll
        for (int n = 0; n < 2; ++n)
#pragma unroll
          for (int j = 0; j < 4; ++j)
            ob[(size_t)(cm0 + wm + m * 16 + l4 * 4 + j) * 512 + wn + n * 16 + l15] =
                (bf16_t)acc[m][n][j];
    }
  }
}

// ---------- y GEMM from f32 B (round-12 verified): 256x128, in-LDS transpose staging ----------
__global__ __launch_bounds__(512, 2)
void k_yf32(const bf16_t* __restrict__ A, const float* __restrict__ Bf,
            float* __restrict__ C, const float* __restrict__ bias) {
  const int raw = blockIdx.x;              // 512 blocks
  const int b = raw & 7, c = raw >> 3;     // XCD-affine: xcd = batch
  const int bm = (c & 1) * 256, bn = (c >> 1) * 128;   // M=512, N=4096
  A  += (size_t)b * 262144;
  Bf += (size_t)b * 512 * 4096;
  C  += (size_t)b * 512 * 4096;

  const int tid = threadIdx.x;
  const int wave = tid >> 6, lane = tid & 63;
  const int l15 = lane & 15, l4 = lane >> 4;
  const int wm = (wave >> 1) * 64, wn = (wave & 1) * 64;
  const int rsw = (l15 >> 1) & 3;

  __shared__ bf16_t As[2][256 * 32];   // 32 KB
  __shared__ bf16_t Bs[2][128 * 32];   // 16 KB
  __shared__ float  Ft[32 * 128];      // 16 KB

  f32x4 acc[4][4] = {};

  const int lrow = lane >> 2;
  const int lch = (lane & 3) ^ ((lane >> 3) & 3);
  const bf16_t* srcA = A + (size_t)(bm + wave * 32 + lrow) * 512 + lch * 8;
  bf16_t* dstA = &As[0][wave * 32 * 32];
  const int bufA = 256 * 32;

  const int fr = tid >> 4, fc = (tid & 15) * 8;
  const float* srcB = Bf + (size_t)fr * 4096 + bn + fc;

  const int tn = tid >> 2, tc = (tid & 3) * 8;
  const int wchunk = ((tid & 3) ^ ((tn >> 1) & 3)) * 8;

  float4 rb0 = *(const float4*)(srcB);
  float4 rb1 = *(const float4*)(srcB + 4);
  gload_lds16(srcA, dstA);
  gload_lds16(srcA + 16 * 512, dstA + 512);
  __syncthreads();

  int cur = 0;
  for (int i = 0; i < 16; ++i) {
    *(float4*)(&Ft[fr * 128 + fc]) = rb0;
    *(float4*)(&Ft[fr * 128 + fc + 4]) = rb1;
    __syncthreads();
    {
      bf16_t tb[8];
#pragma unroll
      for (int q = 0; q < 8; ++q) tb[q] = (bf16_t)Ft[(tc + q) * 128 + tn];
      *(uint4*)(&Bs[cur][tn * 32 + wchunk]) = *(uint4*)tb;
    }
    __syncthreads();
    if (i + 1 < 16) {
      const float* nb = srcB + (size_t)(i + 1) * 32 * 4096;
      rb0 = *(const float4*)(nb);
      rb1 = *(const float4*)(nb + 4);
      gload_lds16(srcA + (i + 1) * 32,            dstA + (cur ^ 1) * bufA);
      gload_lds16(srcA + 16 * 512 + (i + 1) * 32, dstA + (cur ^ 1) * bufA + 512);
    }
    bf16x8 af[4], bfr[4];
#pragma unroll
    for (int n = 0; n < 4; ++n)
      bfr[n] = *(const bf16x8*)(&Bs[cur][(wn + n * 16 + l15) * 32 + ((l4 ^ rsw) * 8)]);
#pragma unroll
    for (int m = 0; m < 4; ++m)
      af[m] = *(const bf16x8*)(&As[cur][(wm + m * 16 + l15) * 32 + ((l4 ^ rsw) * 8)]);
#pragma unroll
    for (int m = 0; m < 4; ++m)
#pragma unroll
      for (int n = 0; n < 4; ++n)
        acc[m][n] = MFMA_16x16x32(af[m], bfr[n], acc[m][n]);
    cur ^= 1;
  }

#pragma unroll
  for (int m = 0; m < 4; ++m) {
    const int row0 = bm + wm + m * 16 + l4 * 4;
#pragma unroll
    for (int n = 0; n < 4; ++n) {
      const int col = bn + wn + n * 16 + l15;
#pragma unroll
      for (int j = 0; j < 4; ++j)
        C[(size_t)(row0 + j) * 4096 + col] = acc[m][n][j] + bias[row0 + j];
    }
  }
}

extern "C" void kernel_launch(void* const* d_in, const int* in_sizes, int n_in,
                              void* d_out, int out_size, void* d_ws, size_t ws_size,
                              hipStream_t stream) {
  const float* f_m  = (const float*)d_in[0];
  const float* f_n  = (const float*)d_in[1];
  const float* Wq   = (const float*)d_in[2];
  const float* Wkv  = (const float*)d_in[3];
  const float* Wout = (const float*)d_in[4];
  const float* bout = (const float*)d_in[5];
  float* y = (float*)d_out;

  const size_t SQ  = (size_t)512 * 512;
  char* p = (char*)d_ws;
  bf16_t* wq_b    = (bf16_t*)p; p += SQ * 2;
  bf16_t* wk_b    = (bf16_t*)p; p += SQ * 2;
  bf16_t* wout_b  = (bf16_t*)p; p += SQ * 2;
  bf16_t* wvT     = (bf16_t*)p; p += SQ * 2;               // [h][c][64]
  bf16_t* Hb      = (bf16_t*)p; p += (size_t)8 * SQ * 2;   // [b][c'][c]
  bf16_t* T1      = (bf16_t*)p; p += (size_t)8 * SQ * 2;   // [b][hi][c']
  bf16_t* wveffT  = (bf16_t*)p; p += (size_t)8 * SQ * 2;   // [b][c][hi]
  bf16_t* W2      = (bf16_t*)p; p += (size_t)8 * SQ * 2;   // [b][o][c]
  bf16_t* Hp8     = (bf16_t*)p; p += (size_t)64 * SQ * 2;  // bf16 split-8 partials

  // gram standalone, 2-deep register prefetch
  k_gram256<<<dim3(256), 512, 0, stream>>>(f_n, f_m, Hp8);
  // reduce8 + weight cvt + Wv transpose in one grid
  k_reduce_prep<<<dim3(2048), 256, 0, stream>>>(Hp8, Hb, Wq, Wkv, Wout,
                                                wq_b, wk_b, wout_b, wvT);

  // T1[b][hi][c'] = sum_c Wq[hi][c] H[b][c'][c]
  k_gemm_bt<<<dim3(4, 4, 8), 256, 0, stream>>>(wq_b, Hb, T1, 512, 512, 512,
                                               0, (long long)SQ, (long long)SQ);
  // dots + softmax + wveff fused
  k_dots_wveff<<<dim3(64), 256, 0, stream>>>(T1, wk_b, wvT, wveffT);
  // W2[b][o][c] = sum_hi Wout[o][hi] WvEffT[b][c][hi]
  k_gemm_bt<<<dim3(4, 4, 8), 256, 0, stream>>>(wout_b, wveffT, W2, 512, 512, 512,
                                               0, (long long)SQ, (long long)SQ);
  // y from f32 f_n directly (in-LDS transpose staging), 256x128 tiles
  k_yf32<<<dim3(512), 512, 0, stream>>>(W2, f_n, y, bout);
}